// Round 8
// baseline (427.280 us; speedup 1.0000x reference)
//
#include <hip/hip_runtime.h>
#include <hip/hip_bf16.h>
#include <stdint.h>

typedef __attribute__((ext_vector_type(8))) short bf16x8;
typedef __attribute__((ext_vector_type(4))) float f32x4;

__device__ __forceinline__ unsigned short f2b(float x) {
  __hip_bfloat16 h = __float2bfloat16(x);
  unsigned short u;
  __builtin_memcpy(&u, &h, 2);
  return u;
}

__device__ __forceinline__ void glds16(const void* g, void* l) {
  __builtin_amdgcn_global_load_lds((const __attribute__((address_space(1))) void*)g,
                                   (__attribute__((address_space(3))) void*)l,
                                   16, 0, 0);
}

__device__ __forceinline__ float wred_add(float v) {
#pragma unroll
  for (int o = 32; o >= 1; o >>= 1) v += __shfl_xor(v, o, 64);
  return v;
}

// ---------------------------------------------------------------------------
// Fused QKV projection GEMM (m97 structure, 128x128 tile, BK=32, 4 waves).
//   z=0: q  = (h@wq + bq) * qscale   (qscale folds 1/sqrt(C) * log2e)
//   z=1: kk = h@wk + bk
//   z=2: vT = h@wv + bv, stored transposed per batch [B][256][4096], with the
//        position index k-permuted within each 32-chunk:
//        pos(k) = ((k>>2)&3)*8 + ((k>>4)&1)*4 + (k&3)
//        so flash's PV A-fragment is one contiguous 16B LDS read.
// ---------------------------------------------------------------------------
__global__ __launch_bounds__(256) void gemm_qkv(
    const unsigned short* __restrict__ h, const unsigned short* __restrict__ wT,
    const float* __restrict__ bq, const float* __restrict__ bk, const float* __restrict__ bv,
    unsigned short* __restrict__ q, unsigned short* __restrict__ kk,
    unsigned short* __restrict__ vT, float qscale)
{
  __shared__ unsigned short As[128 * 32];
  __shared__ unsigned short Bs[128 * 32];
  const int t = threadIdx.x;
  const int lane = t & 63;
  const int wv_ = t >> 6;
  const int wr = wv_ >> 1, wc = wv_ & 1;
  const int z = blockIdx.z;
  const long long row0 = (long long)blockIdx.y * 128;
  const int col0 = blockIdx.x * 128;
  const unsigned short* Bt = wT + z * 65536;
  const float* bias = z == 0 ? bq : z == 1 ? bk : bv;
  const float scale = z == 0 ? qscale : 1.0f;

  const int sr = t >> 2;
  const int sc = (t & 3) * 8;
  const unsigned short* ga = h + (row0 + sr) * 256 + sc;
  const unsigned short* gb = Bt + (col0 + sr) * 256 + sc;
  char* lA = (char*)As + (t >> 6) * 1024;
  char* lB = (char*)Bs + (t >> 6) * 1024;

  const int l15 = lane & 15;
  const int l4 = lane >> 4;
  const unsigned short* pa = As + (wr * 64 + l15) * 32 + l4 * 8;
  const unsigned short* pb = Bs + (wc * 64 + l15) * 32 + l4 * 8;

  f32x4 acc[4][4] = {};

  for (int k0 = 0; k0 < 256; k0 += 32) {
    glds16(ga, lA);
    glds16(ga + 64 * 256, lA + 4096);
    glds16(gb, lB);
    glds16(gb + 64 * 256, lB + 4096);
    ga += 32;
    gb += 32;
    __syncthreads();
    bf16x8 a[4], b[4];
#pragma unroll
    for (int i = 0; i < 4; i++) a[i] = *(const bf16x8*)(pa + i * 512);
#pragma unroll
    for (int j = 0; j < 4; j++) b[j] = *(const bf16x8*)(pb + j * 512);
#pragma unroll
    for (int i = 0; i < 4; i++)
#pragma unroll
      for (int j = 0; j < 4; j++)
        acc[i][j] = __builtin_amdgcn_mfma_f32_16x16x32_bf16(a[i], b[j], acc[i][j], 0, 0, 0);
    __syncthreads();
  }

#pragma unroll
  for (int i = 0; i < 4; i++) {
#pragma unroll
    for (int j = 0; j < 4; j++) {
      const int col = col0 + wc * 64 + j * 16 + l15;
      const float bv_ = bias[col];
#pragma unroll
      for (int r = 0; r < 4; r++) {
        const long long row = row0 + wr * 64 + i * 16 + l4 * 4 + r;
        const float val = (acc[i][j][r] + bv_) * scale;
        if (z == 0) {
          q[row * 256 + col] = f2b(val);
        } else if (z == 1) {
          kk[row * 256 + col] = f2b(val);
        } else {
          const int bb = (int)(row >> 12), rr = (int)(row & 4095);
          const int kl = rr & 31;
          const int rrp = (rr & ~31) | ((((kl >> 2) & 3) << 3) | (((kl >> 4) & 1) << 2) | (kl & 3));
          vT[((long long)bb * 256 + col) * 4096 + rrp] = f2b(val);
        }
      }
    }
  }
}

// ---------------------------------------------------------------------------
// Final projection + residual: out = x + oo@woT + bo   (f32 out)
// ---------------------------------------------------------------------------
__global__ __launch_bounds__(256) void gemm_out(
    const unsigned short* __restrict__ A, const unsigned short* __restrict__ Bt,
    float* __restrict__ C, const float* __restrict__ bias,
    const float* __restrict__ resid)
{
  __shared__ unsigned short As[128 * 32];
  __shared__ unsigned short Bs[128 * 32];
  const int t = threadIdx.x;
  const int lane = t & 63;
  const int wv_ = t >> 6;
  const int wr = wv_ >> 1, wc = wv_ & 1;
  const long long row0 = (long long)blockIdx.y * 128;
  const int col0 = blockIdx.x * 128;

  const int sr = t >> 2;
  const int sc = (t & 3) * 8;
  const unsigned short* ga = A + (row0 + sr) * 256 + sc;
  const unsigned short* gb = Bt + (col0 + sr) * 256 + sc;
  char* lA = (char*)As + (t >> 6) * 1024;
  char* lB = (char*)Bs + (t >> 6) * 1024;

  const int l15 = lane & 15;
  const int l4 = lane >> 4;
  const unsigned short* pa = As + (wr * 64 + l15) * 32 + l4 * 8;
  const unsigned short* pb = Bs + (wc * 64 + l15) * 32 + l4 * 8;

  f32x4 acc[4][4] = {};

  for (int k0 = 0; k0 < 256; k0 += 32) {
    glds16(ga, lA);
    glds16(ga + 64 * 256, lA + 4096);
    glds16(gb, lB);
    glds16(gb + 64 * 256, lB + 4096);
    ga += 32;
    gb += 32;
    __syncthreads();
    bf16x8 a[4], b[4];
#pragma unroll
    for (int i = 0; i < 4; i++) a[i] = *(const bf16x8*)(pa + i * 512);
#pragma unroll
    for (int j = 0; j < 4; j++) b[j] = *(const bf16x8*)(pb + j * 512);
#pragma unroll
    for (int i = 0; i < 4; i++)
#pragma unroll
      for (int j = 0; j < 4; j++)
        acc[i][j] = __builtin_amdgcn_mfma_f32_16x16x32_bf16(a[i], b[j], acc[i][j], 0, 0, 0);
    __syncthreads();
  }

#pragma unroll
  for (int i = 0; i < 4; i++) {
#pragma unroll
    for (int j = 0; j < 4; j++) {
      const int col = col0 + wc * 64 + j * 16 + l15;
      const float bv_ = bias[col];
#pragma unroll
      for (int r = 0; r < 4; r++) {
        const long long row = row0 + wr * 64 + i * 16 + l4 * 4 + r;
        const long long idx = row * 256 + col;
        C[idx] = resid[idx] + acc[i][j][r] + bv_;
      }
    }
  }
}

// ---------------------------------------------------------------------------
// LayerNorm over C=256, one row per block, fp32 in -> bf16 out
// ---------------------------------------------------------------------------
__global__ __launch_bounds__(256) void ln_bf16(const float* __restrict__ x,
                                               const float* __restrict__ gamma,
                                               const float* __restrict__ beta,
                                               unsigned short* __restrict__ h)
{
  const long long row = blockIdx.x;
  const float* xr = x + row * 256;
  const int t = threadIdx.x;
  const float v = xr[t];
  float s = wred_add(v);
  float s2 = wred_add(v * v);
  __shared__ float red[8];
  const int w = t >> 6, lane = t & 63;
  if (lane == 0) { red[w] = s; red[4 + w] = s2; }
  __syncthreads();
  s = red[0] + red[1] + red[2] + red[3];
  s2 = red[4] + red[5] + red[6] + red[7];
  const float mean = s * (1.f / 256.f);
  const float var = s2 * (1.f / 256.f) - mean * mean;
  const float rstd = rsqrtf(var + 1e-3f);
  h[row * 256 + t] = f2b((v - mean) * rstd * gamma[t] + beta[t]);
}

// ---------------------------------------------------------------------------
// Transpose + bf16-cast the four 256x256 weights
// ---------------------------------------------------------------------------
__global__ void wtrans(const float* __restrict__ wq, const float* __restrict__ wk,
                       const float* __restrict__ wv, const float* __restrict__ wo,
                       unsigned short* __restrict__ wT)
{
  const float* w = blockIdx.z == 0 ? wq : blockIdx.z == 1 ? wk : blockIdx.z == 2 ? wv : wo;
  unsigned short* o = wT + (long long)blockIdx.z * 65536;
  __shared__ float tile[16][17];
  const int tx = threadIdx.x, ty = threadIdx.y;
  const int bx = blockIdx.x * 16, by = blockIdx.y * 16;
  tile[ty][tx] = w[(by + ty) * 256 + bx + tx];
  __syncthreads();
  o[(bx + ty) * 256 + (by + tx)] = f2b(tile[tx][ty]);
}

// ---------------------------------------------------------------------------
// Fused flash attention, swapped-operand, qg=4 + d-split.
// grid 256: b = bid&7 (XCD pin), qb = (bid>>3)&15, dh = bid>>7 (d-half).
// 4 waves; wave owns 64 q-rows (4 q-groups of 16); block QBLK=256, d-half=128.
// QK computed per d-half block (duplicated, MFMA-cheap); PV only for d-half.
// KVBLK=64. LDS 96KB: K dbuf 2x32KB @0, V-half dbuf 2x16KB @64K.
// Per wave-iter: 48 ds_read_b128 (K 32 + V 16) feed 192 MFMA (4x FLOP/byte
// of the qg=2 structure -- the DS pipe was the binding resource).
// Main loop: counted vmcnt (12 glds16/wave/tile), raw barrier pair, setprio.
// All operand maps identical to R6/R7 (verified): swapped QK, lambda-slot PV
// with k-permuted vT, K-row swizzle ^((key&7)<<4), V-row ^((d&7)<<4).
// Epilogue: per-wave 8KB slab transpose, writes d-half columns of oo.
// ---------------------------------------------------------------------------
#define FL_LDS (96 * 1024)

__global__ __launch_bounds__(256, 1) void flash(
    const unsigned short* __restrict__ q,   // [B][4096][256] bf16 (scaled by log2e/16)
    const unsigned short* __restrict__ kk,  // [B][4096][256] bf16
    const unsigned short* __restrict__ vT,  // [B][256][4096] bf16, k-permuted per 32
    unsigned short* __restrict__ oo)        // [B][4096][256] bf16
{
  extern __shared__ char lds[];
  const int t = threadIdx.x;
  const int w = t >> 6;
  const int lane = t & 63;
  const int l15 = lane & 15, hi = lane >> 4;
  const int b = blockIdx.x & 7;
  const int qb = (blockIdx.x >> 3) & 15;
  const int dh = blockIdx.x >> 7;  // 0 or 1: which d-half
  const long long qrow = (long long)b * 4096 + (long long)qb * 256 + w * 64;

  const unsigned short* kbase = kk + (long long)b * 4096 * 256;
  const unsigned short* vbase = vT + (long long)b * 256 * 4096;

  // staging sources, pre-swizzled (16B granules):
  //  K tile [64 key][256 c] (512B rows): call p covers keys p*8 + (t>>5);
  //    src granule (t&31) ^ ((t>>5)&7)
  //  V-half tile [128 d][64 k] (128B rows): call p covers d = p*32 + (t>>3);
  //    src granule (t&7) ^ ((t>>3)&7)
  const int gs_k = (t & 31) ^ ((t >> 5) & 7);
  const unsigned short* Kst = kbase + (t >> 5) * 256 + gs_k * 8;
  const int gs_v = (t & 7) ^ ((t >> 3) & 7);
  const unsigned short* Vst = vbase + (long long)(dh * 128 + (t >> 3)) * 4096 + gs_v * 8;

  // Q fragments (B-operand): Qf[qg][ks]: q-row = qrow + qg*16 + l15, k = ks*32 + hi*8
  bf16x8 Qf[4][8];
#pragma unroll
  for (int qg = 0; qg < 4; qg++) {
    const unsigned short* qp = q + (qrow + qg * 16 + l15) * 256 + hi * 8;
#pragma unroll
    for (int ks = 0; ks < 8; ks++) Qf[qg][ks] = *(const bf16x8*)(qp + ks * 32);
  }

  f32x4 O[4][8] = {};
  float mrow[4] = {-1e30f, -1e30f, -1e30f, -1e30f};
  float lrow[4] = {0.f, 0.f, 0.f, 0.f};

  auto stage = [&](int it, int c) {
    const unsigned short* ks_ = Kst + (long long)it * 64 * 256;
    const unsigned short* vs_ = Vst + it * 64;
    char* kd = lds + c * 32768 + w * 1024;
    char* vd = lds + 65536 + c * 16384 + w * 1024;
#pragma unroll
    for (int p = 0; p < 8; p++) glds16(ks_ + p * 8 * 256, kd + p * 4096);
#pragma unroll
    for (int p = 0; p < 4; p++) glds16(vs_ + (long long)p * 32 * 4096, vd + p * 4096);
  };

  stage(0, 0);

  for (int it = 0; it < 64; ++it) {
    const int cur = it & 1;
    __builtin_amdgcn_s_barrier();  // A: all waves done reading buf[cur^1]
    if (it < 63) {
      stage(it + 1, cur ^ 1);
      asm volatile("s_waitcnt vmcnt(12)" ::: "memory");  // tile-it loads done
    } else {
      asm volatile("s_waitcnt vmcnt(0)" ::: "memory");
    }
    __builtin_amdgcn_sched_barrier(0);
    __builtin_amdgcn_s_barrier();  // B: buf[cur] ready for all waves
    const char* Kb = lds + cur * 32768;
    const char* Vb = lds + 65536 + cur * 16384;

    // S^T = K Q^T : 8 k-steps x 4 key-groups; Kf shared across 4 qg
    f32x4 S[4][4] = {};
    __builtin_amdgcn_s_setprio(1);
#pragma unroll
    for (int ks = 0; ks < 8; ks++) {
#pragma unroll
      for (int j = 0; j < 4; j++) {
        bf16x8 Kf = *(const bf16x8*)(Kb + (j * 16 + l15) * 512 +
                                     ((ks * 64 + hi * 16) ^ ((l15 & 7) << 4)));
#pragma unroll
        for (int qg = 0; qg < 4; qg++)
          S[qg][j] = __builtin_amdgcn_mfma_f32_16x16x32_bf16(Kf, Qf[qg][ks], S[qg][j], 0, 0, 0);
      }
    }
    __builtin_amdgcn_s_setprio(0);

    // online softmax, in-lane (lane owns one q-row per qg), + P pack
    bf16x8 PfA[4], PfB[4];
#pragma unroll
    for (int qg = 0; qg < 4; qg++) {
      float mx = -1e30f;
#pragma unroll
      for (int j = 0; j < 4; j++)
#pragma unroll
        for (int r = 0; r < 4; r++) mx = fmaxf(mx, S[qg][j][r]);
      mx = fmaxf(mx, __shfl_xor(mx, 16, 64));
      mx = fmaxf(mx, __shfl_xor(mx, 32, 64));
      const float mn = fmaxf(mrow[qg], mx);
      const float rs_ = exp2f(mrow[qg] - mn);
      mrow[qg] = mn;
      float sum = 0.f;
      float e[4][4];
#pragma unroll
      for (int j = 0; j < 4; j++)
#pragma unroll
        for (int r = 0; r < 4; r++) {
          e[j][r] = exp2f(S[qg][j][r] - mn);
          sum += e[j][r];
        }
      sum += __shfl_xor(sum, 16, 64);
      sum += __shfl_xor(sum, 32, 64);
      lrow[qg] = lrow[qg] * rs_ + sum;
      bf16x8 pa_, pb_;
#pragma unroll
      for (int j = 0; j < 2; j++)
#pragma unroll
        for (int r = 0; r < 4; r++) {
          pa_[j * 4 + r] = (short)f2b(e[j][r]);
          pb_[j * 4 + r] = (short)f2b(e[j + 2][r]);
        }
      PfA[qg] = pa_;
      PfB[qg] = pb_;
#pragma unroll
      for (int dg = 0; dg < 8; dg++) O[qg][dg] *= rs_;
    }

    // PV: O^T += V' P'  (two 32-key chunks; V-frags shared across 4 qg)
    __builtin_amdgcn_s_setprio(1);
#pragma unroll
    for (int dg = 0; dg < 8; dg++) {
      const char* vrow = Vb + (dg * 16 + l15) * 128;
      const int swz = (l15 & 7) << 4;
      bf16x8 Vf0 = *(const bf16x8*)(vrow + ((hi * 16) ^ swz));
      bf16x8 Vf1 = *(const bf16x8*)(vrow + ((64 + hi * 16) ^ swz));
#pragma unroll
      for (int qg = 0; qg < 4; qg++) {
        O[qg][dg] = __builtin_amdgcn_mfma_f32_16x16x32_bf16(Vf0, PfA[qg], O[qg][dg], 0, 0, 0);
        O[qg][dg] = __builtin_amdgcn_mfma_f32_16x16x32_bf16(Vf1, PfB[qg], O[qg][dg], 0, 0, 0);
      }
    }
    __builtin_amdgcn_s_setprio(0);
  }

  // epilogue: O^T/l -> transpose via per-wave 8KB LDS slab -> oo[q][d-half]
  __syncthreads();  // everyone done with K/V buffers
  char* const slab = lds + w * 8192;
#pragma unroll
  for (int qg = 0; qg < 4; qg++) {
    const float inv = 1.f / lrow[qg];
#pragma unroll
    for (int dg = 0; dg < 8; dg++) {
      f32x4 v = O[qg][dg] * inv;
      *(f32x4*)(slab + l15 * 512 + ((dg * 64 + hi * 16) ^ ((l15 & 7) << 4))) = v;
    }
    // read rows: lane handles q-row = lane>>2, d-chunk = (lane&3)*32 of the half
    const int qq = lane >> 2;
    const int dc = lane & 3;
    const long long orow = (qrow + qg * 16 + qq) * 256 + dh * 128 + dc * 32;
#pragma unroll
    for (int st = 0; st < 4; st++) {
      bf16x8 pack;
#pragma unroll
      for (int di = 0; di < 2; di++) {
        f32x4 v = *(const f32x4*)(slab + qq * 512 +
                                  ((dc * 128 + st * 32 + di * 16) ^ ((qq & 7) << 4)));
#pragma unroll
        for (int e2 = 0; e2 < 4; e2++) pack[di * 4 + e2] = (short)f2b(v[e2]);
      }
      *(bf16x8*)(oo + orow + st * 8) = pack;
    }
  }
}

// ---------------------------------------------------------------------------
extern "C" void kernel_launch(void* const* d_in, const int* in_sizes, int n_in,
                              void* d_out, int out_size, void* d_ws, size_t ws_size,
                              hipStream_t stream)
{
  const float* x = (const float*)d_in[0];
  const float* gamma = (const float*)d_in[1];
  const float* beta = (const float*)d_in[2];
  const float* wq = (const float*)d_in[3];
  const float* bq = (const float*)d_in[4];
  const float* wk = (const float*)d_in[5];
  const float* bk = (const float*)d_in[6];
  const float* wv = (const float*)d_in[7];
  const float* bv = (const float*)d_in[8];
  const float* wo = (const float*)d_in[9];
  const float* bo = (const float*)d_in[10];

  const int Cc = 256;
  const long long MR = 32768;  // 8 * 4096

  char* base = (char*)d_ws;
  size_t off = 0;
  auto take = [&](size_t bytes) -> char* {
    char* p = base + off;
    off = (off + bytes + 255) & ~(size_t)255;
    return p;
  };
  unsigned short* h  = (unsigned short*)take((size_t)MR * Cc * 2);
  unsigned short* q  = (unsigned short*)take((size_t)MR * Cc * 2);  // scaled
  unsigned short* kk = (unsigned short*)take((size_t)MR * Cc * 2);
  unsigned short* vT = (unsigned short*)take((size_t)MR * Cc * 2);  // [B][C][4096] k-perm
  unsigned short* oo = (unsigned short*)take((size_t)MR * Cc * 2);
  unsigned short* wT = (unsigned short*)take(4ull * Cc * Cc * 2);

  wtrans<<<dim3(16, 16, 4), dim3(16, 16), 0, stream>>>(wq, wk, wv, wo, wT);
  ln_bf16<<<dim3((unsigned)MR), dim3(256), 0, stream>>>(x, gamma, beta, h);

  const float qscale = 0.0625f * 1.44269504f;  // 1/sqrt(256) * log2(e)
  gemm_qkv<<<dim3(2, 256, 3), 256, 0, stream>>>(h, wT, bq, bk, bv, q, kk, vT, qscale);

  flash<<<dim3(256), dim3(256), FL_LDS, stream>>>(q, kk, vT, oo);

  gemm_out<<<dim3(2, 256, 1), 256, 0, stream>>>(oo, wT + 3 * 65536, (float*)d_out, bo, x);
}

// Round 9
// 277.449 us; speedup vs baseline: 1.5400x; 1.5400x over previous
//
#include <hip/hip_runtime.h>
#include <hip/hip_bf16.h>
#include <stdint.h>

typedef __attribute__((ext_vector_type(8))) short bf16x8;
typedef __attribute__((ext_vector_type(4))) float f32x4;

__device__ __forceinline__ unsigned short f2b(float x) {
  __hip_bfloat16 h = __float2bfloat16(x);
  unsigned short u;
  __builtin_memcpy(&u, &h, 2);
  return u;
}

__device__ __forceinline__ float b2f(unsigned short u) {
  unsigned v = (unsigned)u << 16;
  float f;
  __builtin_memcpy(&f, &v, 4);
  return f;
}

__device__ __forceinline__ void glds16(const void* g, void* l) {
  __builtin_amdgcn_global_load_lds((const __attribute__((address_space(1))) void*)g,
                                   (__attribute__((address_space(3))) void*)l,
                                   16, 0, 0);
}

__device__ __forceinline__ float wred_add(float v) {
#pragma unroll
  for (int o = 32; o >= 1; o >>= 1) v += __shfl_xor(v, o, 64);
  return v;
}

// ---------------------------------------------------------------------------
// Fused QKV projection GEMM (m97 structure, 128x128 tile, BK=32, 4 waves).
//   z=0: q  = (h@wq + bq) * qscale   (qscale folds 1/sqrt(C) * log2e)
//   z=1: kk = h@wk + bk
//   z=2: vT = h@wv + bv, stored transposed per batch [B][256][4096], with the
//        position index k-permuted within each 32-chunk:
//        pos(k) = ((k>>2)&3)*8 + ((k>>4)&1)*4 + (k&3)
//        so flash's PV A-fragment is one contiguous 16B LDS read.
// ---------------------------------------------------------------------------
__global__ __launch_bounds__(256) void gemm_qkv(
    const unsigned short* __restrict__ h, const unsigned short* __restrict__ wT,
    const float* __restrict__ bq, const float* __restrict__ bk, const float* __restrict__ bv,
    unsigned short* __restrict__ q, unsigned short* __restrict__ kk,
    unsigned short* __restrict__ vT, float qscale)
{
  __shared__ unsigned short As[128 * 32];
  __shared__ unsigned short Bs[128 * 32];
  const int t = threadIdx.x;
  const int lane = t & 63;
  const int wv_ = t >> 6;
  const int wr = wv_ >> 1, wc = wv_ & 1;
  const int z = blockIdx.z;
  const long long row0 = (long long)blockIdx.y * 128;
  const int col0 = blockIdx.x * 128;
  const unsigned short* Bt = wT + z * 65536;
  const float* bias = z == 0 ? bq : z == 1 ? bk : bv;
  const float scale = z == 0 ? qscale : 1.0f;

  const int sr = t >> 2;
  const int sc = (t & 3) * 8;
  const unsigned short* ga = h + (row0 + sr) * 256 + sc;
  const unsigned short* gb = Bt + (col0 + sr) * 256 + sc;
  char* lA = (char*)As + (t >> 6) * 1024;
  char* lB = (char*)Bs + (t >> 6) * 1024;

  const int l15 = lane & 15;
  const int l4 = lane >> 4;
  const unsigned short* pa = As + (wr * 64 + l15) * 32 + l4 * 8;
  const unsigned short* pb = Bs + (wc * 64 + l15) * 32 + l4 * 8;

  f32x4 acc[4][4] = {};

  for (int k0 = 0; k0 < 256; k0 += 32) {
    glds16(ga, lA);
    glds16(ga + 64 * 256, lA + 4096);
    glds16(gb, lB);
    glds16(gb + 64 * 256, lB + 4096);
    ga += 32;
    gb += 32;
    __syncthreads();
    bf16x8 a[4], b[4];
#pragma unroll
    for (int i = 0; i < 4; i++) a[i] = *(const bf16x8*)(pa + i * 512);
#pragma unroll
    for (int j = 0; j < 4; j++) b[j] = *(const bf16x8*)(pb + j * 512);
#pragma unroll
    for (int i = 0; i < 4; i++)
#pragma unroll
      for (int j = 0; j < 4; j++)
        acc[i][j] = __builtin_amdgcn_mfma_f32_16x16x32_bf16(a[i], b[j], acc[i][j], 0, 0, 0);
    __syncthreads();
  }

#pragma unroll
  for (int i = 0; i < 4; i++) {
#pragma unroll
    for (int j = 0; j < 4; j++) {
      const int col = col0 + wc * 64 + j * 16 + l15;
      const float bv_ = bias[col];
#pragma unroll
      for (int r = 0; r < 4; r++) {
        const long long row = row0 + wr * 64 + i * 16 + l4 * 4 + r;
        const float val = (acc[i][j][r] + bv_) * scale;
        if (z == 0) {
          q[row * 256 + col] = f2b(val);
        } else if (z == 1) {
          kk[row * 256 + col] = f2b(val);
        } else {
          const int bb = (int)(row >> 12), rr = (int)(row & 4095);
          const int kl = rr & 31;
          const int rrp = (rr & ~31) | ((((kl >> 2) & 3) << 3) | (((kl >> 4) & 1) << 2) | (kl & 3));
          vT[((long long)bb * 256 + col) * 4096 + rrp] = f2b(val);
        }
      }
    }
  }
}

// ---------------------------------------------------------------------------
// Final projection + residual: out = x + oo@woT + bo   (f32 out)
// ---------------------------------------------------------------------------
__global__ __launch_bounds__(256) void gemm_out(
    const unsigned short* __restrict__ A, const unsigned short* __restrict__ Bt,
    float* __restrict__ C, const float* __restrict__ bias,
    const float* __restrict__ resid)
{
  __shared__ unsigned short As[128 * 32];
  __shared__ unsigned short Bs[128 * 32];
  const int t = threadIdx.x;
  const int lane = t & 63;
  const int wv_ = t >> 6;
  const int wr = wv_ >> 1, wc = wv_ & 1;
  const long long row0 = (long long)blockIdx.y * 128;
  const int col0 = blockIdx.x * 128;

  const int sr = t >> 2;
  const int sc = (t & 3) * 8;
  const unsigned short* ga = A + (row0 + sr) * 256 + sc;
  const unsigned short* gb = Bt + (col0 + sr) * 256 + sc;
  char* lA = (char*)As + (t >> 6) * 1024;
  char* lB = (char*)Bs + (t >> 6) * 1024;

  const int l15 = lane & 15;
  const int l4 = lane >> 4;
  const unsigned short* pa = As + (wr * 64 + l15) * 32 + l4 * 8;
  const unsigned short* pb = Bs + (wc * 64 + l15) * 32 + l4 * 8;

  f32x4 acc[4][4] = {};

  for (int k0 = 0; k0 < 256; k0 += 32) {
    glds16(ga, lA);
    glds16(ga + 64 * 256, lA + 4096);
    glds16(gb, lB);
    glds16(gb + 64 * 256, lB + 4096);
    ga += 32;
    gb += 32;
    __syncthreads();
    bf16x8 a[4], b[4];
#pragma unroll
    for (int i = 0; i < 4; i++) a[i] = *(const bf16x8*)(pa + i * 512);
#pragma unroll
    for (int j = 0; j < 4; j++) b[j] = *(const bf16x8*)(pb + j * 512);
#pragma unroll
    for (int i = 0; i < 4; i++)
#pragma unroll
      for (int j = 0; j < 4; j++)
        acc[i][j] = __builtin_amdgcn_mfma_f32_16x16x32_bf16(a[i], b[j], acc[i][j], 0, 0, 0);
    __syncthreads();
  }

#pragma unroll
  for (int i = 0; i < 4; i++) {
#pragma unroll
    for (int j = 0; j < 4; j++) {
      const int col = col0 + wc * 64 + j * 16 + l15;
      const float bv_ = bias[col];
#pragma unroll
      for (int r = 0; r < 4; r++) {
        const long long row = row0 + wr * 64 + i * 16 + l4 * 4 + r;
        const long long idx = row * 256 + col;
        C[idx] = resid[idx] + acc[i][j][r] + bv_;
      }
    }
  }
}

// ---------------------------------------------------------------------------
// LayerNorm over C=256, one row per block, fp32 in -> bf16 out
// ---------------------------------------------------------------------------
__global__ __launch_bounds__(256) void ln_bf16(const float* __restrict__ x,
                                               const float* __restrict__ gamma,
                                               const float* __restrict__ beta,
                                               unsigned short* __restrict__ h)
{
  const long long row = blockIdx.x;
  const float* xr = x + row * 256;
  const int t = threadIdx.x;
  const float v = xr[t];
  float s = wred_add(v);
  float s2 = wred_add(v * v);
  __shared__ float red[8];
  const int w = t >> 6, lane = t & 63;
  if (lane == 0) { red[w] = s; red[4 + w] = s2; }
  __syncthreads();
  s = red[0] + red[1] + red[2] + red[3];
  s2 = red[4] + red[5] + red[6] + red[7];
  const float mean = s * (1.f / 256.f);
  const float var = s2 * (1.f / 256.f) - mean * mean;
  const float rstd = rsqrtf(var + 1e-3f);
  h[row * 256 + t] = f2b((v - mean) * rstd * gamma[t] + beta[t]);
}

// ---------------------------------------------------------------------------
// Transpose + bf16-cast the four 256x256 weights
// ---------------------------------------------------------------------------
__global__ void wtrans(const float* __restrict__ wq, const float* __restrict__ wk,
                       const float* __restrict__ wv, const float* __restrict__ wo,
                       unsigned short* __restrict__ wT)
{
  const float* w = blockIdx.z == 0 ? wq : blockIdx.z == 1 ? wk : blockIdx.z == 2 ? wv : wo;
  unsigned short* o = wT + (long long)blockIdx.z * 65536;
  __shared__ float tile[16][17];
  const int tx = threadIdx.x, ty = threadIdx.y;
  const int bx = blockIdx.x * 16, by = blockIdx.y * 16;
  tile[ty][tx] = w[(by + ty) * 256 + bx + tx];
  __syncthreads();
  o[(bx + ty) * 256 + (by + tx)] = f2b(tile[tx][ty]);
}

// ---------------------------------------------------------------------------
// Fused flash attention, swapped-operand, KV-SPLIT (flash-decoding style).
// grid 512: b = bid&7 (XCD pin), kh = (bid>>3)&1 (key-half), qb = bid>>4.
// Each block processes keys [kh*2048, kh*2048+2048) = 64 iters of KVBLK=32,
// and writes UNNORMALIZED partial O (bf16) + per-row (m,l) f32; merge_halves
// combines. 2 blocks/CU (64KB LDS each, VGPR~128) -> 8 waves/CU: the other
// block's waves cover this block's barrier/softmax/LDS-latency stalls.
// Inner structure byte-identical to the verified R6 kernel (maps proven):
//  - swapped QK: S^T = mfma(K,Q), lane owns q-row qg*16+l15
//  - PV lambda-slot pairing with k-permuted vT; Vf8 = one b128 read
//  - K rows swizzled ^((key&7)<<4); V rows ^((d&3)<<4); pre-swizzled sources
//  - epilogue slab transpose (no 1/l normalize here; merge does it)
// ---------------------------------------------------------------------------
#define FL_LDS (64 * 1024)

__global__ __launch_bounds__(256, 2) void flash(
    const unsigned short* __restrict__ q,   // [B][4096][256] bf16 (scaled by log2e/16)
    const unsigned short* __restrict__ kk,  // [B][4096][256] bf16
    const unsigned short* __restrict__ vT,  // [B][256][4096] bf16, k-permuted per 32
    unsigned short* __restrict__ o0,        // [B][4096][256] partial, kh=0
    unsigned short* __restrict__ o1,        // [B][4096][256] partial, kh=1
    float2* __restrict__ ml0,               // [B*4096] (m,l) kh=0
    float2* __restrict__ ml1)               // [B*4096] (m,l) kh=1
{
  extern __shared__ char lds[];
  const int t = threadIdx.x;
  const int w = t >> 6;
  const int lane = t & 63;
  const int l15 = lane & 15, hi = lane >> 4;
  const int b = blockIdx.x & 7;
  const int kh = (blockIdx.x >> 3) & 1;
  const int qb = blockIdx.x >> 4;
  const long long qrow = (long long)b * 4096 + (long long)qb * 128 + w * 32;

  const unsigned short* kbase = kk + (long long)b * 4096 * 256 + (long long)kh * 2048 * 256;
  const unsigned short* vbase = vT + (long long)b * 256 * 4096 + kh * 2048;

  // staging sources, pre-swizzled (16B granules):
  //  K tile [32 key][256 c]: call p covers keys p*8+(t>>5); src granule (t&31)^((t>>5)&7)
  //  V tile [256 d][32 k]:   call p covers d = p*64+(t>>2); src granule (t&3)^((t>>2)&3)
  const int gs_k = (t & 31) ^ ((t >> 5) & 7);
  const unsigned short* Kst = kbase + (t >> 5) * 256 + gs_k * 8;
  const int gs_v = (t & 3) ^ ((t >> 2) & 3);
  const unsigned short* Vst = vbase + (long long)(t >> 2) * 4096 + gs_v * 8;

  // Q fragments (B-operand): Qf[qg][ks]: q-row = qrow + qg*16 + l15, k = ks*32 + hi*8
  bf16x8 Qf[2][8];
#pragma unroll
  for (int qg = 0; qg < 2; qg++) {
    const unsigned short* qp = q + (qrow + qg * 16 + l15) * 256 + hi * 8;
#pragma unroll
    for (int ks = 0; ks < 8; ks++) Qf[qg][ks] = *(const bf16x8*)(qp + ks * 32);
  }

  f32x4 O[2][16] = {};
  float mrow[2] = {-1e30f, -1e30f};
  float lrow[2] = {0.f, 0.f};

  auto stage = [&](int it, int c) {
    const unsigned short* ks_ = Kst + (long long)it * 32 * 256;
    const unsigned short* vs_ = Vst + it * 32;
    char* kd = lds + c * 16384 + w * 1024;
    char* vd = lds + 32768 + c * 16384 + w * 1024;
#pragma unroll
    for (int p = 0; p < 4; p++) {
      glds16(ks_ + p * 8 * 256, kd + p * 4096);
      glds16(vs_ + (long long)p * 64 * 4096, vd + p * 4096);
    }
  };

  stage(0, 0);

  for (int it = 0; it < 64; ++it) {
    const int cur = it & 1;
    __syncthreads();  // buf[cur] staged (vmcnt drained at barrier)
    if (it < 63) stage(it + 1, cur ^ 1);
    const char* Kb = lds + cur * 16384;
    const char* Vb = lds + 32768 + cur * 16384;

    // S^T = K Q^T : per (j, qg): 8 k-steps of 16x16x32
    f32x4 S[2][2] = {};
    __builtin_amdgcn_s_setprio(1);
#pragma unroll
    for (int ks = 0; ks < 8; ks++) {
#pragma unroll
      for (int j = 0; j < 2; j++) {
        bf16x8 Kf = *(const bf16x8*)(Kb + (j * 16 + l15) * 512 +
                                     ((ks * 64 + hi * 16) ^ ((l15 & 7) << 4)));
        S[0][j] = __builtin_amdgcn_mfma_f32_16x16x32_bf16(Kf, Qf[0][ks], S[0][j], 0, 0, 0);
        S[1][j] = __builtin_amdgcn_mfma_f32_16x16x32_bf16(Kf, Qf[1][ks], S[1][j], 0, 0, 0);
      }
    }
    __builtin_amdgcn_s_setprio(0);

    // online softmax, in-lane (lane owns one q-row per qg), + P pack (bf16x8)
    bf16x8 Pf8[2];
#pragma unroll
    for (int qg = 0; qg < 2; qg++) {
      float mx = fmaxf(fmaxf(fmaxf(S[qg][0][0], S[qg][0][1]), fmaxf(S[qg][0][2], S[qg][0][3])),
                       fmaxf(fmaxf(S[qg][1][0], S[qg][1][1]), fmaxf(S[qg][1][2], S[qg][1][3])));
      mx = fmaxf(mx, __shfl_xor(mx, 16, 64));
      mx = fmaxf(mx, __shfl_xor(mx, 32, 64));
      const float mn = fmaxf(mrow[qg], mx);
      const float rs_ = exp2f(mrow[qg] - mn);
      mrow[qg] = mn;
      float sum = 0.f;
      float e[2][4];
#pragma unroll
      for (int j = 0; j < 2; j++)
#pragma unroll
        for (int r = 0; r < 4; r++) {
          e[j][r] = exp2f(S[qg][j][r] - mn);
          sum += e[j][r];
        }
      sum += __shfl_xor(sum, 16, 64);
      sum += __shfl_xor(sum, 32, 64);
      lrow[qg] = lrow[qg] * rs_ + sum;
      bf16x8 p;
#pragma unroll
      for (int j = 0; j < 2; j++)
#pragma unroll
        for (int r = 0; r < 4; r++) p[j * 4 + r] = (short)f2b(e[j][r]);
      Pf8[qg] = p;
#pragma unroll
      for (int dg = 0; dg < 16; dg++) O[qg][dg] *= rs_;
    }

    // PV: O^T += V' P'  (one 16x16x32 per (qg,dg); V-frag shared across qg)
    __builtin_amdgcn_s_setprio(1);
#pragma unroll
    for (int dg = 0; dg < 16; dg++) {
      bf16x8 Vf8 = *(const bf16x8*)(Vb + (dg * 16 + l15) * 64 +
                                    ((hi * 16) ^ ((l15 & 3) << 4)));
      O[0][dg] = __builtin_amdgcn_mfma_f32_16x16x32_bf16(Vf8, Pf8[0], O[0][dg], 0, 0, 0);
      O[1][dg] = __builtin_amdgcn_mfma_f32_16x16x32_bf16(Vf8, Pf8[1], O[1][dg], 0, 0, 0);
    }
    __builtin_amdgcn_s_setprio(0);
  }

  // epilogue: UNNORMALIZED O^T -> transpose via per-wave 16KB slab -> partial out
  unsigned short* const op = kh ? o1 : o0;
  float2* const mlp = kh ? ml1 : ml0;
  __syncthreads();  // everyone done with K/V buffers
  char* const slab = lds + w * 16384;
#pragma unroll
  for (int qg = 0; qg < 2; qg++) {
#pragma unroll
    for (int dg = 0; dg < 16; dg++) {
      f32x4 v = O[qg][dg];
      *(f32x4*)(slab + l15 * 1024 + ((dg * 64 + hi * 16) ^ ((l15 & 7) << 4))) = v;
    }
    if (hi == 0) mlp[qrow + qg * 16 + l15] = make_float2(mrow[qg], lrow[qg]);
    // read rows: lane handles q-row = lane>>2, d-chunk = (lane&3)*64 (FULL 64)
    const int qq = lane >> 2;
    const int dc = lane & 3;
    const long long orow = (qrow + qg * 16 + qq) * 256 + dc * 64;
#pragma unroll
    for (int half = 0; half < 8; half++) {
      bf16x8 pack;
#pragma unroll
      for (int di = 0; di < 2; di++) {
        f32x4 v = *(const f32x4*)(slab + qq * 1024 +
                                  ((dc * 256 + half * 32 + di * 16) ^ ((qq & 7) << 4)));
#pragma unroll
        for (int e2 = 0; e2 < 4; e2++) pack[di * 4 + e2] = (short)f2b(v[e2]);
      }
      *(bf16x8*)(op + orow + half * 8) = pack;
    }
    __syncthreads();  // slab reuse between qg passes
  }
}

// ---------------------------------------------------------------------------
// Merge the two KV-half partials: out = (w0*O0 + w1*O1) / (w0*l0 + w1*l1),
// w_i = exp2(m_i - max(m0,m1)). In-place into o0 (aliased as oo downstream).
// 8 rows per 256-thr block; 32 thr/row, 8 bf16 elems per thread.
// ---------------------------------------------------------------------------
__global__ __launch_bounds__(256) void merge_halves(
    unsigned short* __restrict__ o0, const unsigned short* __restrict__ o1,
    const float2* __restrict__ ml0, const float2* __restrict__ ml1)
{
  const int t = threadIdx.x;
  const long long row = (long long)blockIdx.x * 8 + (t >> 5);
  const int ch = t & 31;
  const float2 a = ml0[row];
  const float2 c = ml1[row];
  const float M = fmaxf(a.x, c.x);
  const float w0 = exp2f(a.x - M);
  const float w1 = exp2f(c.x - M);
  const float inv = 1.f / (w0 * a.y + w1 * c.y);
  const long long idx = row * 256 + ch * 8;
  bf16x8 u0 = *(const bf16x8*)(o0 + idx);
  bf16x8 u1 = *(const bf16x8*)(o1 + idx);
  bf16x8 out;
#pragma unroll
  for (int e = 0; e < 8; e++) {
    const float v = (w0 * b2f((unsigned short)u0[e]) + w1 * b2f((unsigned short)u1[e])) * inv;
    out[e] = (short)f2b(v);
  }
  *(bf16x8*)(o0 + idx) = out;
}

// ---------------------------------------------------------------------------
extern "C" void kernel_launch(void* const* d_in, const int* in_sizes, int n_in,
                              void* d_out, int out_size, void* d_ws, size_t ws_size,
                              hipStream_t stream)
{
  const float* x = (const float*)d_in[0];
  const float* gamma = (const float*)d_in[1];
  const float* beta = (const float*)d_in[2];
  const float* wq = (const float*)d_in[3];
  const float* bq = (const float*)d_in[4];
  const float* wk = (const float*)d_in[5];
  const float* bk = (const float*)d_in[6];
  const float* wv = (const float*)d_in[7];
  const float* bv = (const float*)d_in[8];
  const float* wo = (const float*)d_in[9];
  const float* bo = (const float*)d_in[10];

  const int Cc = 256;
  const long long MR = 32768;  // 8 * 4096

  char* base = (char*)d_ws;
  size_t off = 0;
  auto take = [&](size_t bytes) -> char* {
    char* p = base + off;
    off = (off + bytes + 255) & ~(size_t)255;
    return p;
  };
  unsigned short* h   = (unsigned short*)take((size_t)MR * Cc * 2);
  unsigned short* q   = (unsigned short*)take((size_t)MR * Cc * 2);  // scaled
  unsigned short* kk  = (unsigned short*)take((size_t)MR * Cc * 2);
  unsigned short* vT  = (unsigned short*)take((size_t)MR * Cc * 2);  // [B][C][4096] k-perm
  unsigned short* oo  = (unsigned short*)take((size_t)MR * Cc * 2);  // partial kh=0, then merged
  unsigned short* o1  = (unsigned short*)take((size_t)MR * Cc * 2);  // partial kh=1
  unsigned short* wT  = (unsigned short*)take(4ull * Cc * Cc * 2);
  float2* ml0 = (float2*)take((size_t)MR * sizeof(float2));
  float2* ml1 = (float2*)take((size_t)MR * sizeof(float2));

  wtrans<<<dim3(16, 16, 4), dim3(16, 16), 0, stream>>>(wq, wk, wv, wo, wT);
  ln_bf16<<<dim3((unsigned)MR), dim3(256), 0, stream>>>(x, gamma, beta, h);

  const float qscale = 0.0625f * 1.44269504f;  // 1/sqrt(256) * log2(e)
  gemm_qkv<<<dim3(2, 256, 3), 256, 0, stream>>>(h, wT, bq, bk, bv, q, kk, vT, qscale);

  flash<<<dim3(512), dim3(256), FL_LDS, stream>>>(q, kk, vT, oo, o1, ml0, ml1);
  merge_halves<<<dim3((unsigned)(MR / 8)), dim3(256), 0, stream>>>(oo, o1, ml0, ml1);

  gemm_out<<<dim3(2, 256, 1), 256, 0, stream>>>(oo, wT + 3 * 65536, (float*)d_out, bo, x);
}

// Round 10
// 252.222 us; speedup vs baseline: 1.6941x; 1.1000x over previous
//
#include <hip/hip_runtime.h>
#include <hip/hip_bf16.h>
#include <stdint.h>

typedef __attribute__((ext_vector_type(8))) short bf16x8;
typedef __attribute__((ext_vector_type(4))) short s16x4;
typedef __attribute__((ext_vector_type(4))) float f32x4;

__device__ __forceinline__ unsigned short f2b(float x) {
  __hip_bfloat16 h = __float2bfloat16(x);
  unsigned short u;
  __builtin_memcpy(&u, &h, 2);
  return u;
}

__device__ __forceinline__ float b2f(unsigned short u) {
  unsigned v = (unsigned)u << 16;
  float f;
  __builtin_memcpy(&f, &v, 4);
  return f;
}

__device__ __forceinline__ void glds16(const void* g, void* l) {
  __builtin_amdgcn_global_load_lds((const __attribute__((address_space(1))) void*)g,
                                   (__attribute__((address_space(3))) void*)l,
                                   16, 0, 0);
}

__device__ __forceinline__ float wred_add(float v) {
#pragma unroll
  for (int o = 32; o >= 1; o >>= 1) v += __shfl_xor(v, o, 64);
  return v;
}

// ---------------------------------------------------------------------------
// Fused QKV projection GEMM (m97 structure, 128x128 tile, BK=32, 4 waves).
//   z=0: q  = (h@wq + bq) * qscale   (qscale folds 1/sqrt(C) * log2e)
//   z=1: kk = h@wk + bk
//   z=2: vT = h@wv + bv, stored transposed per batch [B][256][4096], with the
//        position index k-permuted within each 32-chunk:
//        pos(k) = ((k>>2)&3)*8 + ((k>>4)&1)*4 + (k&3)
//        so flash's PV A-fragment is one contiguous 16B LDS read.
// ---------------------------------------------------------------------------
__global__ __launch_bounds__(256) void gemm_qkv(
    const unsigned short* __restrict__ h, const unsigned short* __restrict__ wT,
    const float* __restrict__ bq, const float* __restrict__ bk, const float* __restrict__ bv,
    unsigned short* __restrict__ q, unsigned short* __restrict__ kk,
    unsigned short* __restrict__ vT, float qscale)
{
  __shared__ unsigned short As[128 * 32];
  __shared__ unsigned short Bs[128 * 32];
  const int t = threadIdx.x;
  const int lane = t & 63;
  const int wv_ = t >> 6;
  const int wr = wv_ >> 1, wc = wv_ & 1;
  const int z = blockIdx.z;
  const long long row0 = (long long)blockIdx.y * 128;
  const int col0 = blockIdx.x * 128;
  const unsigned short* Bt = wT + z * 65536;
  const float* bias = z == 0 ? bq : z == 1 ? bk : bv;
  const float scale = z == 0 ? qscale : 1.0f;

  const int sr = t >> 2;
  const int sc = (t & 3) * 8;
  const unsigned short* ga = h + (row0 + sr) * 256 + sc;
  const unsigned short* gb = Bt + (col0 + sr) * 256 + sc;
  char* lA = (char*)As + (t >> 6) * 1024;
  char* lB = (char*)Bs + (t >> 6) * 1024;

  const int l15 = lane & 15;
  const int l4 = lane >> 4;
  const unsigned short* pa = As + (wr * 64 + l15) * 32 + l4 * 8;
  const unsigned short* pb = Bs + (wc * 64 + l15) * 32 + l4 * 8;

  f32x4 acc[4][4] = {};

  for (int k0 = 0; k0 < 256; k0 += 32) {
    glds16(ga, lA);
    glds16(ga + 64 * 256, lA + 4096);
    glds16(gb, lB);
    glds16(gb + 64 * 256, lB + 4096);
    ga += 32;
    gb += 32;
    __syncthreads();
    bf16x8 a[4], b[4];
#pragma unroll
    for (int i = 0; i < 4; i++) a[i] = *(const bf16x8*)(pa + i * 512);
#pragma unroll
    for (int j = 0; j < 4; j++) b[j] = *(const bf16x8*)(pb + j * 512);
#pragma unroll
    for (int i = 0; i < 4; i++)
#pragma unroll
      for (int j = 0; j < 4; j++)
        acc[i][j] = __builtin_amdgcn_mfma_f32_16x16x32_bf16(a[i], b[j], acc[i][j], 0, 0, 0);
    __syncthreads();
  }

#pragma unroll
  for (int i = 0; i < 4; i++) {
#pragma unroll
    for (int j = 0; j < 4; j++) {
      const int col = col0 + wc * 64 + j * 16 + l15;
      const float bv_ = bias[col];
#pragma unroll
      for (int r = 0; r < 4; r++) {
        const long long row = row0 + wr * 64 + i * 16 + l4 * 4 + r;
        const float val = (acc[i][j][r] + bv_) * scale;
        if (z == 0) {
          q[row * 256 + col] = f2b(val);
        } else if (z == 1) {
          kk[row * 256 + col] = f2b(val);
        } else {
          const int bb = (int)(row >> 12), rr = (int)(row & 4095);
          const int kl = rr & 31;
          const int rrp = (rr & ~31) | ((((kl >> 2) & 3) << 3) | (((kl >> 4) & 1) << 2) | (kl & 3));
          vT[((long long)bb * 256 + col) * 4096 + rrp] = f2b(val);
        }
      }
    }
  }
}

// ---------------------------------------------------------------------------
// Final projection + residual: out = x + oo@woT + bo   (f32 out)
// ---------------------------------------------------------------------------
__global__ __launch_bounds__(256) void gemm_out(
    const unsigned short* __restrict__ A, const unsigned short* __restrict__ Bt,
    float* __restrict__ C, const float* __restrict__ bias,
    const float* __restrict__ resid)
{
  __shared__ unsigned short As[128 * 32];
  __shared__ unsigned short Bs[128 * 32];
  const int t = threadIdx.x;
  const int lane = t & 63;
  const int wv_ = t >> 6;
  const int wr = wv_ >> 1, wc = wv_ & 1;
  const long long row0 = (long long)blockIdx.y * 128;
  const int col0 = blockIdx.x * 128;

  const int sr = t >> 2;
  const int sc = (t & 3) * 8;
  const unsigned short* ga = A + (row0 + sr) * 256 + sc;
  const unsigned short* gb = Bt + (col0 + sr) * 256 + sc;
  char* lA = (char*)As + (t >> 6) * 1024;
  char* lB = (char*)Bs + (t >> 6) * 1024;

  const int l15 = lane & 15;
  const int l4 = lane >> 4;
  const unsigned short* pa = As + (wr * 64 + l15) * 32 + l4 * 8;
  const unsigned short* pb = Bs + (wc * 64 + l15) * 32 + l4 * 8;

  f32x4 acc[4][4] = {};

  for (int k0 = 0; k0 < 256; k0 += 32) {
    glds16(ga, lA);
    glds16(ga + 64 * 256, lA + 4096);
    glds16(gb, lB);
    glds16(gb + 64 * 256, lB + 4096);
    ga += 32;
    gb += 32;
    __syncthreads();
    bf16x8 a[4], b[4];
#pragma unroll
    for (int i = 0; i < 4; i++) a[i] = *(const bf16x8*)(pa + i * 512);
#pragma unroll
    for (int j = 0; j < 4; j++) b[j] = *(const bf16x8*)(pb + j * 512);
#pragma unroll
    for (int i = 0; i < 4; i++)
#pragma unroll
      for (int j = 0; j < 4; j++)
        acc[i][j] = __builtin_amdgcn_mfma_f32_16x16x32_bf16(a[i], b[j], acc[i][j], 0, 0, 0);
    __syncthreads();
  }

#pragma unroll
  for (int i = 0; i < 4; i++) {
#pragma unroll
    for (int j = 0; j < 4; j++) {
      const int col = col0 + wc * 64 + j * 16 + l15;
      const float bv_ = bias[col];
#pragma unroll
      for (int r = 0; r < 4; r++) {
        const long long row = row0 + wr * 64 + i * 16 + l4 * 4 + r;
        const long long idx = row * 256 + col;
        C[idx] = resid[idx] + acc[i][j][r] + bv_;
      }
    }
  }
}

// ---------------------------------------------------------------------------
// LayerNorm over C=256: one WAVE per row (4 f32 per lane), 8 rows per block.
// ---------------------------------------------------------------------------
__global__ __launch_bounds__(512) void ln_bf16(const float* __restrict__ x,
                                               const float* __restrict__ gamma,
                                               const float* __restrict__ beta,
                                               unsigned short* __restrict__ h)
{
  const int w = threadIdx.x >> 6;
  const int lane = threadIdx.x & 63;
  const long long row = (long long)blockIdx.x * 8 + w;
  const f32x4 v = *(const f32x4*)(x + row * 256 + lane * 4);
  const f32x4 g = *(const f32x4*)(gamma + lane * 4);
  const f32x4 be = *(const f32x4*)(beta + lane * 4);
  float s = v[0] + v[1] + v[2] + v[3];
  float s2 = v[0] * v[0] + v[1] * v[1] + v[2] * v[2] + v[3] * v[3];
#pragma unroll
  for (int o = 32; o >= 1; o >>= 1) {
    s += __shfl_xor(s, o, 64);
    s2 += __shfl_xor(s2, o, 64);
  }
  const float mean = s * (1.f / 256.f);
  const float var = s2 * (1.f / 256.f) - mean * mean;
  const float rstd = rsqrtf(var + 1e-3f);
  s16x4 out;
#pragma unroll
  for (int e = 0; e < 4; e++) out[e] = (short)f2b((v[e] - mean) * rstd * g[e] + be[e]);
  *(s16x4*)(h + row * 256 + lane * 4) = out;
}

// ---------------------------------------------------------------------------
// Transpose + bf16-cast the four 256x256 weights
// ---------------------------------------------------------------------------
__global__ void wtrans(const float* __restrict__ wq, const float* __restrict__ wk,
                       const float* __restrict__ wv, const float* __restrict__ wo,
                       unsigned short* __restrict__ wT)
{
  const float* w = blockIdx.z == 0 ? wq : blockIdx.z == 1 ? wk : blockIdx.z == 2 ? wv : wo;
  unsigned short* o = wT + (long long)blockIdx.z * 65536;
  __shared__ float tile[16][17];
  const int tx = threadIdx.x, ty = threadIdx.y;
  const int bx = blockIdx.x * 16, by = blockIdx.y * 16;
  tile[ty][tx] = w[(by + ty) * 256 + bx + tx];
  __syncthreads();
  o[(bx + ty) * 256 + (by + tx)] = f2b(tile[tx][ty]);
}

// ---------------------------------------------------------------------------
// Fused flash attention, swapped-operand, KV-SPLIT + counted vmcnt (T4).
// grid 512: b = bid&7 (XCD pin), kh = (bid>>3)&1 (key-half), qb = bid>>4.
// Each block: keys [kh*2048, +2048) = 64 iters of KVBLK=32; writes
// UNNORMALIZED partial O (bf16) + (m,l); merge_halves combines.
// 2 blocks/CU (64KB LDS, VGPR~128) -> 8 waves/CU.
// Main loop: raw barrier pair + s_waitcnt vmcnt(8) (never 0 in-loop): the
// next tile's 8 loads/wave stay in flight across compute (T4; the R9
// __syncthreads forced a full drain every iter).
// T13 defer-rescale: skip O-rescale + m-update when the whole wave's tile
// max grew by <= 8 (P bounded by 2^8; merge is invariant to stale m).
// Operand maps identical to R6/R9 (verified): swapped QK, lambda-slot PV
// with k-permuted vT, K rows swizzled ^((key&7)<<4), V rows ^((d&3)<<4),
// pre-swizzled global staging sources, slab-transpose epilogue.
// ---------------------------------------------------------------------------
#define FL_LDS (64 * 1024)

__global__ __launch_bounds__(256, 2) void flash(
    const unsigned short* __restrict__ q,   // [B][4096][256] bf16 (scaled by log2e/16)
    const unsigned short* __restrict__ kk,  // [B][4096][256] bf16
    const unsigned short* __restrict__ vT,  // [B][256][4096] bf16, k-permuted per 32
    unsigned short* __restrict__ o0,        // [B][4096][256] partial, kh=0
    unsigned short* __restrict__ o1,        // [B][4096][256] partial, kh=1
    float2* __restrict__ ml0,               // [B*4096] (m,l) kh=0
    float2* __restrict__ ml1)               // [B*4096] (m,l) kh=1
{
  extern __shared__ char lds[];
  const int t = threadIdx.x;
  const int w = t >> 6;
  const int lane = t & 63;
  const int l15 = lane & 15, hi = lane >> 4;
  const int b = blockIdx.x & 7;
  const int kh = (blockIdx.x >> 3) & 1;
  const int qb = blockIdx.x >> 4;
  const long long qrow = (long long)b * 4096 + (long long)qb * 128 + w * 32;

  const unsigned short* kbase = kk + (long long)b * 4096 * 256 + (long long)kh * 2048 * 256;
  const unsigned short* vbase = vT + (long long)b * 256 * 4096 + kh * 2048;

  const int gs_k = (t & 31) ^ ((t >> 5) & 7);
  const unsigned short* Kst = kbase + (t >> 5) * 256 + gs_k * 8;
  const int gs_v = (t & 3) ^ ((t >> 2) & 3);
  const unsigned short* Vst = vbase + (long long)(t >> 2) * 4096 + gs_v * 8;

  // Q fragments (B-operand): Qf[qg][ks]: q-row = qrow + qg*16 + l15, k = ks*32 + hi*8
  bf16x8 Qf[2][8];
#pragma unroll
  for (int qg = 0; qg < 2; qg++) {
    const unsigned short* qp = q + (qrow + qg * 16 + l15) * 256 + hi * 8;
#pragma unroll
    for (int ks = 0; ks < 8; ks++) Qf[qg][ks] = *(const bf16x8*)(qp + ks * 32);
  }

  f32x4 O[2][16] = {};
  float mrow[2] = {-1e30f, -1e30f};
  float lrow[2] = {0.f, 0.f};

  auto stage = [&](int it, int c) {
    const unsigned short* ks_ = Kst + (long long)it * 32 * 256;
    const unsigned short* vs_ = Vst + it * 32;
    char* kd = lds + c * 16384 + w * 1024;
    char* vd = lds + 32768 + c * 16384 + w * 1024;
#pragma unroll
    for (int p = 0; p < 4; p++) {
      glds16(ks_ + p * 8 * 256, kd + p * 4096);
      glds16(vs_ + (long long)p * 64 * 4096, vd + p * 4096);
    }
  };

  stage(0, 0);

  for (int it = 0; it < 64; ++it) {
    const int cur = it & 1;
    __builtin_amdgcn_s_barrier();  // A: all waves done reading buf[cur^1]
    if (it < 63) {
      stage(it + 1, cur ^ 1);
      asm volatile("s_waitcnt vmcnt(8)" ::: "memory");  // tile-it loads done
    } else {
      asm volatile("s_waitcnt vmcnt(0)" ::: "memory");
    }
    __builtin_amdgcn_sched_barrier(0);
    __builtin_amdgcn_s_barrier();  // B: buf[cur] ready for all waves
    const char* Kb = lds + cur * 16384;
    const char* Vb = lds + 32768 + cur * 16384;

    // S^T = K Q^T : per (j, qg): 8 k-steps of 16x16x32
    f32x4 S[2][2] = {};
    __builtin_amdgcn_s_setprio(1);
#pragma unroll
    for (int ks = 0; ks < 8; ks++) {
#pragma unroll
      for (int j = 0; j < 2; j++) {
        bf16x8 Kf = *(const bf16x8*)(Kb + (j * 16 + l15) * 512 +
                                     ((ks * 64 + hi * 16) ^ ((l15 & 7) << 4)));
        S[0][j] = __builtin_amdgcn_mfma_f32_16x16x32_bf16(Kf, Qf[0][ks], S[0][j], 0, 0, 0);
        S[1][j] = __builtin_amdgcn_mfma_f32_16x16x32_bf16(Kf, Qf[1][ks], S[1][j], 0, 0, 0);
      }
    }
    __builtin_amdgcn_s_setprio(0);

    // online softmax, in-lane; T13 defer-rescale (wave-uniform skip)
    bf16x8 Pf8[2];
#pragma unroll
    for (int qg = 0; qg < 2; qg++) {
      float mx = fmaxf(fmaxf(fmaxf(S[qg][0][0], S[qg][0][1]), fmaxf(S[qg][0][2], S[qg][0][3])),
                       fmaxf(fmaxf(S[qg][1][0], S[qg][1][1]), fmaxf(S[qg][1][2], S[qg][1][3])));
      mx = fmaxf(mx, __shfl_xor(mx, 16, 64));
      mx = fmaxf(mx, __shfl_xor(mx, 32, 64));
      if (!__all(mx <= mrow[qg] + 8.f)) {
        const float mn = fmaxf(mrow[qg], mx);
        const float rs_ = exp2f(mrow[qg] - mn);
        mrow[qg] = mn;
        lrow[qg] *= rs_;
#pragma unroll
        for (int dg = 0; dg < 16; dg++) O[qg][dg] *= rs_;
      }
      float sum = 0.f;
      float e[2][4];
#pragma unroll
      for (int j = 0; j < 2; j++)
#pragma unroll
        for (int r = 0; r < 4; r++) {
          e[j][r] = exp2f(S[qg][j][r] - mrow[qg]);
          sum += e[j][r];
        }
      sum += __shfl_xor(sum, 16, 64);
      sum += __shfl_xor(sum, 32, 64);
      lrow[qg] += sum;
      bf16x8 p;
#pragma unroll
      for (int j = 0; j < 2; j++)
#pragma unroll
        for (int r = 0; r < 4; r++) p[j * 4 + r] = (short)f2b(e[j][r]);
      Pf8[qg] = p;
    }

    // PV: O^T += V' P'  (one 16x16x32 per (qg,dg); V-frag shared across qg)
    __builtin_amdgcn_s_setprio(1);
#pragma unroll
    for (int dg = 0; dg < 16; dg++) {
      bf16x8 Vf8 = *(const bf16x8*)(Vb + (dg * 16 + l15) * 64 +
                                    ((hi * 16) ^ ((l15 & 3) << 4)));
      O[0][dg] = __builtin_amdgcn_mfma_f32_16x16x32_bf16(Vf8, Pf8[0], O[0][dg], 0, 0, 0);
      O[1][dg] = __builtin_amdgcn_mfma_f32_16x16x32_bf16(Vf8, Pf8[1], O[1][dg], 0, 0, 0);
    }
    __builtin_amdgcn_s_setprio(0);
  }

  // epilogue: UNNORMALIZED O^T -> transpose via per-wave 16KB slab -> partial out
  unsigned short* const op = kh ? o1 : o0;
  float2* const mlp = kh ? ml1 : ml0;
  __syncthreads();  // everyone done with K/V buffers
  char* const slab = lds + w * 16384;
#pragma unroll
  for (int qg = 0; qg < 2; qg++) {
#pragma unroll
    for (int dg = 0; dg < 16; dg++) {
      f32x4 v = O[qg][dg];
      *(f32x4*)(slab + l15 * 1024 + ((dg * 64 + hi * 16) ^ ((l15 & 7) << 4))) = v;
    }
    if (hi == 0) mlp[qrow + qg * 16 + l15] = make_float2(mrow[qg], lrow[qg]);
    const int qq = lane >> 2;
    const int dc = lane & 3;
    const long long orow = (qrow + qg * 16 + qq) * 256 + dc * 64;
#pragma unroll
    for (int half = 0; half < 8; half++) {
      bf16x8 pack;
#pragma unroll
      for (int di = 0; di < 2; di++) {
        f32x4 v = *(const f32x4*)(slab + qq * 1024 +
                                  ((dc * 256 + half * 32 + di * 16) ^ ((qq & 7) << 4)));
#pragma unroll
        for (int e2 = 0; e2 < 4; e2++) pack[di * 4 + e2] = (short)f2b(v[e2]);
      }
      *(bf16x8*)(op + orow + half * 8) = pack;
    }
    __syncthreads();  // slab reuse between qg passes
  }
}

// ---------------------------------------------------------------------------
// Merge the two KV-half partials: out = (w0*O0 + w1*O1) / (w0*l0 + w1*l1),
// w_i = exp2(m_i - max(m0,m1)). In-place into o0.
// ---------------------------------------------------------------------------
__global__ __launch_bounds__(256) void merge_halves(
    unsigned short* __restrict__ o0, const unsigned short* __restrict__ o1,
    const float2* __restrict__ ml0, const float2* __restrict__ ml1)
{
  const int t = threadIdx.x;
  const long long row = (long long)blockIdx.x * 8 + (t >> 5);
  const int ch = t & 31;
  const float2 a = ml0[row];
  const float2 c = ml1[row];
  const float M = fmaxf(a.x, c.x);
  const float w0 = exp2f(a.x - M);
  const float w1 = exp2f(c.x - M);
  const float inv = 1.f / (w0 * a.y + w1 * c.y);
  const long long idx = row * 256 + ch * 8;
  bf16x8 u0 = *(const bf16x8*)(o0 + idx);
  bf16x8 u1 = *(const bf16x8*)(o1 + idx);
  bf16x8 out;
#pragma unroll
  for (int e = 0; e < 8; e++) {
    const float v = (w0 * b2f((unsigned short)u0[e]) + w1 * b2f((unsigned short)u1[e])) * inv;
    out[e] = (short)f2b(v);
  }
  *(bf16x8*)(o0 + idx) = out;
}

// ---------------------------------------------------------------------------
extern "C" void kernel_launch(void* const* d_in, const int* in_sizes, int n_in,
                              void* d_out, int out_size, void* d_ws, size_t ws_size,
                              hipStream_t stream)
{
  const float* x = (const float*)d_in[0];
  const float* gamma = (const float*)d_in[1];
  const float* beta = (const float*)d_in[2];
  const float* wq = (const float*)d_in[3];
  const float* bq = (const float*)d_in[4];
  const float* wk = (const float*)d_in[5];
  const float* bk = (const float*)d_in[6];
  const float* wv = (const float*)d_in[7];
  const float* bv = (const float*)d_in[8];
  const float* wo = (const float*)d_in[9];
  const float* bo = (const float*)d_in[10];

  const int Cc = 256;
  const long long MR = 32768;  // 8 * 4096

  char* base = (char*)d_ws;
  size_t off = 0;
  auto take = [&](size_t bytes) -> char* {
    char* p = base + off;
    off = (off + bytes + 255) & ~(size_t)255;
    return p;
  };
  unsigned short* h   = (unsigned short*)take((size_t)MR * Cc * 2);
  unsigned short* q   = (unsigned short*)take((size_t)MR * Cc * 2);  // scaled
  unsigned short* kk  = (unsigned short*)take((size_t)MR * Cc * 2);
  unsigned short* vT  = (unsigned short*)take((size_t)MR * Cc * 2);  // [B][C][4096] k-perm
  unsigned short* oo  = (unsigned short*)take((size_t)MR * Cc * 2);  // partial kh=0, then merged
  unsigned short* o1  = (unsigned short*)take((size_t)MR * Cc * 2);  // partial kh=1
  unsigned short* wT  = (unsigned short*)take(4ull * Cc * Cc * 2);
  float2* ml0 = (float2*)take((size_t)MR * sizeof(float2));
  float2* ml1 = (float2*)take((size_t)MR * sizeof(float2));

  wtrans<<<dim3(16, 16, 4), dim3(16, 16), 0, stream>>>(wq, wk, wv, wo, wT);
  ln_bf16<<<dim3((unsigned)(MR / 8)), dim3(512), 0, stream>>>(x, gamma, beta, h);

  const float qscale = 0.0625f * 1.44269504f;  // 1/sqrt(256) * log2(e)
  gemm_qkv<<<dim3(2, 256, 3), 256, 0, stream>>>(h, wT, bq, bk, bv, q, kk, vT, qscale);

  flash<<<dim3(512), dim3(256), FL_LDS, stream>>>(q, kk, vT, oo, o1, ml0, ml1);
  merge_halves<<<dim3((unsigned)(MR / 8)), dim3(256), 0, stream>>>(oo, o1, ml0, ml1);

  gemm_out<<<dim3(2, 256, 1), 256, 0, stream>>>(oo, wT + 3 * 65536, (float*)d_out, bo, x);
}

// Round 11
// 228.360 us; speedup vs baseline: 1.8711x; 1.1045x over previous
//
#include <hip/hip_runtime.h>
#include <hip/hip_bf16.h>
#include <stdint.h>

typedef __attribute__((ext_vector_type(8))) short bf16x8;
typedef __attribute__((ext_vector_type(4))) short s16x4;
typedef __attribute__((ext_vector_type(4))) float f32x4;

__device__ __forceinline__ unsigned short f2b(float x) {
  __hip_bfloat16 h = __float2bfloat16(x);
  unsigned short u;
  __builtin_memcpy(&u, &h, 2);
  return u;
}

__device__ __forceinline__ float b2f(unsigned short u) {
  unsigned v = (unsigned)u << 16;
  float f;
  __builtin_memcpy(&f, &v, 4);
  return f;
}

__device__ __forceinline__ void glds16(const void* g, void* l) {
  __builtin_amdgcn_global_load_lds((const __attribute__((address_space(1))) void*)g,
                                   (__attribute__((address_space(3))) void*)l,
                                   16, 0, 0);
}

// ---------------------------------------------------------------------------
// Fused QKV projection GEMM (m97 structure, 128x128 tile, BK=32, 4 waves).
//   z=0: q  = (h@wq + bq) * qscale   (qscale folds 1/sqrt(C) * log2e)
//   z=1: kk = h@wk + bk
//   z=2: vT = h@wv + bv, stored transposed per batch [B][256][4096], with the
//        position index k-permuted within each 32-chunk:
//        pos(k) = ((k>>2)&3)*8 + ((k>>4)&1)*4 + (k&3)
//        so flash's PV A-fragment is one contiguous 16B LDS read.
// ---------------------------------------------------------------------------
__global__ __launch_bounds__(256) void gemm_qkv(
    const unsigned short* __restrict__ h, const unsigned short* __restrict__ wT,
    const float* __restrict__ bq, const float* __restrict__ bk, const float* __restrict__ bv,
    unsigned short* __restrict__ q, unsigned short* __restrict__ kk,
    unsigned short* __restrict__ vT, float qscale)
{
  __shared__ unsigned short As[128 * 32];
  __shared__ unsigned short Bs[128 * 32];
  const int t = threadIdx.x;
  const int lane = t & 63;
  const int wv_ = t >> 6;
  const int wr = wv_ >> 1, wc = wv_ & 1;
  const int z = blockIdx.z;
  const long long row0 = (long long)blockIdx.y * 128;
  const int col0 = blockIdx.x * 128;
  const unsigned short* Bt = wT + z * 65536;
  const float* bias = z == 0 ? bq : z == 1 ? bk : bv;
  const float scale = z == 0 ? qscale : 1.0f;

  const int sr = t >> 2;
  const int sc = (t & 3) * 8;
  const unsigned short* ga = h + (row0 + sr) * 256 + sc;
  const unsigned short* gb = Bt + (col0 + sr) * 256 + sc;
  char* lA = (char*)As + (t >> 6) * 1024;
  char* lB = (char*)Bs + (t >> 6) * 1024;

  const int l15 = lane & 15;
  const int l4 = lane >> 4;
  const unsigned short* pa = As + (wr * 64 + l15) * 32 + l4 * 8;
  const unsigned short* pb = Bs + (wc * 64 + l15) * 32 + l4 * 8;

  f32x4 acc[4][4] = {};

  for (int k0 = 0; k0 < 256; k0 += 32) {
    glds16(ga, lA);
    glds16(ga + 64 * 256, lA + 4096);
    glds16(gb, lB);
    glds16(gb + 64 * 256, lB + 4096);
    ga += 32;
    gb += 32;
    __syncthreads();
    bf16x8 a[4], b[4];
#pragma unroll
    for (int i = 0; i < 4; i++) a[i] = *(const bf16x8*)(pa + i * 512);
#pragma unroll
    for (int j = 0; j < 4; j++) b[j] = *(const bf16x8*)(pb + j * 512);
#pragma unroll
    for (int i = 0; i < 4; i++)
#pragma unroll
      for (int j = 0; j < 4; j++)
        acc[i][j] = __builtin_amdgcn_mfma_f32_16x16x32_bf16(a[i], b[j], acc[i][j], 0, 0, 0);
    __syncthreads();
  }

#pragma unroll
  for (int i = 0; i < 4; i++) {
#pragma unroll
    for (int j = 0; j < 4; j++) {
      const int col = col0 + wc * 64 + j * 16 + l15;
      const float bv_ = bias[col];
#pragma unroll
      for (int r = 0; r < 4; r++) {
        const long long row = row0 + wr * 64 + i * 16 + l4 * 4 + r;
        const float val = (acc[i][j][r] + bv_) * scale;
        if (z == 0) {
          q[row * 256 + col] = f2b(val);
        } else if (z == 1) {
          kk[row * 256 + col] = f2b(val);
        } else {
          const int bb = (int)(row >> 12), rr = (int)(row & 4095);
          const int kl = rr & 31;
          const int rrp = (rr & ~31) | ((((kl >> 2) & 3) << 3) | (((kl >> 4) & 1) << 2) | (kl & 3));
          vT[((long long)bb * 256 + col) * 4096 + rrp] = f2b(val);
        }
      }
    }
  }
}

// ---------------------------------------------------------------------------
// Final projection + residual with FUSED KV-half merge:
//   A[row] = (f0*o0[row] + f1*o1[row]) where f_i = w_i / (w0*l0 + w1*l1),
//   out = x + A@woT + bo   (f32 out)
// A-staging: reg-load both partials, merge in VALU, ds_write to the SAME
// linear LDS layout the glds16 path produced (byte offset t*16 / +4096).
// ---------------------------------------------------------------------------
__global__ __launch_bounds__(256) void gemm_out(
    const unsigned short* __restrict__ o0, const unsigned short* __restrict__ o1,
    const float2* __restrict__ ml0, const float2* __restrict__ ml1,
    const unsigned short* __restrict__ Bt,
    float* __restrict__ C, const float* __restrict__ bias,
    const float* __restrict__ resid)
{
  __shared__ unsigned short As[128 * 32];
  __shared__ unsigned short Bs[128 * 32];
  const int t = threadIdx.x;
  const int lane = t & 63;
  const int wv_ = t >> 6;
  const int wr = wv_ >> 1, wc = wv_ & 1;
  const long long row0 = (long long)blockIdx.y * 128;
  const int col0 = blockIdx.x * 128;

  const int sr = t >> 2;
  const int sc = (t & 3) * 8;
  const long long ar0 = row0 + sr;
  // per-row merge factors (rows ar0 and ar0+64)
  float f0a, f1a, f0b, f1b;
  {
    const float2 a = ml0[ar0], c = ml1[ar0];
    const float M = fmaxf(a.x, c.x);
    const float w0 = exp2f(a.x - M), w1 = exp2f(c.x - M);
    const float inv = 1.f / (w0 * a.y + w1 * c.y);
    f0a = w0 * inv;
    f1a = w1 * inv;
  }
  {
    const float2 a = ml0[ar0 + 64], c = ml1[ar0 + 64];
    const float M = fmaxf(a.x, c.x);
    const float w0 = exp2f(a.x - M), w1 = exp2f(c.x - M);
    const float inv = 1.f / (w0 * a.y + w1 * c.y);
    f0b = w0 * inv;
    f1b = w1 * inv;
  }
  const unsigned short* g0 = o0 + ar0 * 256 + sc;
  const unsigned short* g1 = o1 + ar0 * 256 + sc;
  const unsigned short* gb = Bt + (col0 + sr) * 256 + sc;
  char* lB = (char*)Bs + (t >> 6) * 1024;

  const int l15 = lane & 15;
  const int l4 = lane >> 4;
  const unsigned short* pa = As + (wr * 64 + l15) * 32 + l4 * 8;
  const unsigned short* pb = Bs + (wc * 64 + l15) * 32 + l4 * 8;

  f32x4 acc[4][4] = {};

  for (int k0 = 0; k0 < 256; k0 += 32) {
    bf16x8 u0 = *(const bf16x8*)g0;
    bf16x8 u1 = *(const bf16x8*)g1;
    bf16x8 v0 = *(const bf16x8*)(g0 + 64 * 256);
    bf16x8 v1 = *(const bf16x8*)(g1 + 64 * 256);
    bf16x8 m0, m1;
#pragma unroll
    for (int e = 0; e < 8; e++) {
      m0[e] = (short)f2b(f0a * b2f((unsigned short)u0[e]) + f1a * b2f((unsigned short)u1[e]));
      m1[e] = (short)f2b(f0b * b2f((unsigned short)v0[e]) + f1b * b2f((unsigned short)v1[e]));
    }
    *(bf16x8*)((char*)As + t * 16) = m0;
    *(bf16x8*)((char*)As + 4096 + t * 16) = m1;
    glds16(gb, lB);
    glds16(gb + 64 * 256, lB + 4096);
    g0 += 32;
    g1 += 32;
    gb += 32;
    __syncthreads();
    bf16x8 a[4], b[4];
#pragma unroll
    for (int i = 0; i < 4; i++) a[i] = *(const bf16x8*)(pa + i * 512);
#pragma unroll
    for (int j = 0; j < 4; j++) b[j] = *(const bf16x8*)(pb + j * 512);
#pragma unroll
    for (int i = 0; i < 4; i++)
#pragma unroll
      for (int j = 0; j < 4; j++)
        acc[i][j] = __builtin_amdgcn_mfma_f32_16x16x32_bf16(a[i], b[j], acc[i][j], 0, 0, 0);
    __syncthreads();
  }

#pragma unroll
  for (int i = 0; i < 4; i++) {
#pragma unroll
    for (int j = 0; j < 4; j++) {
      const int col = col0 + wc * 64 + j * 16 + l15;
      const float bv_ = bias[col];
#pragma unroll
      for (int r = 0; r < 4; r++) {
        const long long row = row0 + wr * 64 + i * 16 + l4 * 4 + r;
        const long long idx = row * 256 + col;
        C[idx] = resid[idx] + acc[i][j][r] + bv_;
      }
    }
  }
}

// ---------------------------------------------------------------------------
// LayerNorm over C=256: one WAVE per row (4 f32 per lane), 8 rows per block.
// ---------------------------------------------------------------------------
__global__ __launch_bounds__(512) void ln_bf16(const float* __restrict__ x,
                                               const float* __restrict__ gamma,
                                               const float* __restrict__ beta,
                                               unsigned short* __restrict__ h)
{
  const int w = threadIdx.x >> 6;
  const int lane = threadIdx.x & 63;
  const long long row = (long long)blockIdx.x * 8 + w;
  const f32x4 v = *(const f32x4*)(x + row * 256 + lane * 4);
  const f32x4 g = *(const f32x4*)(gamma + lane * 4);
  const f32x4 be = *(const f32x4*)(beta + lane * 4);
  float s = v[0] + v[1] + v[2] + v[3];
  float s2 = v[0] * v[0] + v[1] * v[1] + v[2] * v[2] + v[3] * v[3];
#pragma unroll
  for (int o = 32; o >= 1; o >>= 1) {
    s += __shfl_xor(s, o, 64);
    s2 += __shfl_xor(s2, o, 64);
  }
  const float mean = s * (1.f / 256.f);
  const float var = s2 * (1.f / 256.f) - mean * mean;
  const float rstd = rsqrtf(var + 1e-3f);
  s16x4 out;
#pragma unroll
  for (int e = 0; e < 4; e++) out[e] = (short)f2b((v[e] - mean) * rstd * g[e] + be[e]);
  *(s16x4*)(h + row * 256 + lane * 4) = out;
}

// ---------------------------------------------------------------------------
// Transpose + bf16-cast the four 256x256 weights
// ---------------------------------------------------------------------------
__global__ void wtrans(const float* __restrict__ wq, const float* __restrict__ wk,
                       const float* __restrict__ wv, const float* __restrict__ wo,
                       unsigned short* __restrict__ wT)
{
  const float* w = blockIdx.z == 0 ? wq : blockIdx.z == 1 ? wk : blockIdx.z == 2 ? wv : wo;
  unsigned short* o = wT + (long long)blockIdx.z * 65536;
  __shared__ float tile[16][17];
  const int tx = threadIdx.x, ty = threadIdx.y;
  const int bx = blockIdx.x * 16, by = blockIdx.y * 16;
  tile[ty][tx] = w[(by + ty) * 256 + bx + tx];
  __syncthreads();
  o[(bx + ty) * 256 + (by + tx)] = f2b(tile[tx][ty]);
}

// ---------------------------------------------------------------------------
// Fused flash attention, swapped-operand, KV-SPLIT + counted vmcnt (T4).
// grid 512: b = bid&7 (XCD pin), kh = (bid>>3)&1 (key-half), qb = bid>>4.
// 2 blocks/CU (64KB LDS, VGPR~128) -> 8 waves/CU.
// R11: shfl-free common path --
//  (1) defer-max check on the IN-LANE max: __all(mxl <= m+8) is equivalent
//      to the wave-max check; the 2 max-shfls move inside the rare branch.
//  (2) lrow kept as PER-LANE partial; reduced across hi once in the epilogue.
//  m stays wave-uniform (only updated on the reduced trigger path).
// Operand maps identical to R6/R9/R10 (verified).
// ---------------------------------------------------------------------------
#define FL_LDS (64 * 1024)

__global__ __launch_bounds__(256, 2) void flash(
    const unsigned short* __restrict__ q,   // [B][4096][256] bf16 (scaled by log2e/16)
    const unsigned short* __restrict__ kk,  // [B][4096][256] bf16
    const unsigned short* __restrict__ vT,  // [B][256][4096] bf16, k-permuted per 32
    unsigned short* __restrict__ o0,        // [B][4096][256] partial, kh=0
    unsigned short* __restrict__ o1,        // [B][4096][256] partial, kh=1
    float2* __restrict__ ml0,               // [B*4096] (m,l) kh=0
    float2* __restrict__ ml1)               // [B*4096] (m,l) kh=1
{
  extern __shared__ char lds[];
  const int t = threadIdx.x;
  const int w = t >> 6;
  const int lane = t & 63;
  const int l15 = lane & 15, hi = lane >> 4;
  const int b = blockIdx.x & 7;
  const int kh = (blockIdx.x >> 3) & 1;
  const int qb = blockIdx.x >> 4;
  const long long qrow = (long long)b * 4096 + (long long)qb * 128 + w * 32;

  const unsigned short* kbase = kk + (long long)b * 4096 * 256 + (long long)kh * 2048 * 256;
  const unsigned short* vbase = vT + (long long)b * 256 * 4096 + kh * 2048;

  const int gs_k = (t & 31) ^ ((t >> 5) & 7);
  const unsigned short* Kst = kbase + (t >> 5) * 256 + gs_k * 8;
  const int gs_v = (t & 3) ^ ((t >> 2) & 3);
  const unsigned short* Vst = vbase + (long long)(t >> 2) * 4096 + gs_v * 8;

  // Q fragments (B-operand): Qf[qg][ks]: q-row = qrow + qg*16 + l15, k = ks*32 + hi*8
  bf16x8 Qf[2][8];
#pragma unroll
  for (int qg = 0; qg < 2; qg++) {
    const unsigned short* qp = q + (qrow + qg * 16 + l15) * 256 + hi * 8;
#pragma unroll
    for (int ks = 0; ks < 8; ks++) Qf[qg][ks] = *(const bf16x8*)(qp + ks * 32);
  }

  f32x4 O[2][16] = {};
  float mrow[2] = {-1e30f, -1e30f};
  float lrow[2] = {0.f, 0.f};  // PER-LANE partial sums (reduced in epilogue)

  auto stage = [&](int it, int c) {
    const unsigned short* ks_ = Kst + (long long)it * 32 * 256;
    const unsigned short* vs_ = Vst + it * 32;
    char* kd = lds + c * 16384 + w * 1024;
    char* vd = lds + 32768 + c * 16384 + w * 1024;
#pragma unroll
    for (int p = 0; p < 4; p++) {
      glds16(ks_ + p * 8 * 256, kd + p * 4096);
      glds16(vs_ + (long long)p * 64 * 4096, vd + p * 4096);
    }
  };

  stage(0, 0);

  for (int it = 0; it < 64; ++it) {
    const int cur = it & 1;
    __builtin_amdgcn_s_barrier();  // A: all waves done reading buf[cur^1]
    if (it < 63) {
      stage(it + 1, cur ^ 1);
      asm volatile("s_waitcnt vmcnt(8)" ::: "memory");  // tile-it loads done
    } else {
      asm volatile("s_waitcnt vmcnt(0)" ::: "memory");
    }
    __builtin_amdgcn_sched_barrier(0);
    __builtin_amdgcn_s_barrier();  // B: buf[cur] ready for all waves
    const char* Kb = lds + cur * 16384;
    const char* Vb = lds + 32768 + cur * 16384;

    // S^T = K Q^T : per (j, qg): 8 k-steps of 16x16x32
    f32x4 S[2][2] = {};
    __builtin_amdgcn_s_setprio(1);
#pragma unroll
    for (int ks = 0; ks < 8; ks++) {
#pragma unroll
      for (int j = 0; j < 2; j++) {
        bf16x8 Kf = *(const bf16x8*)(Kb + (j * 16 + l15) * 512 +
                                     ((ks * 64 + hi * 16) ^ ((l15 & 7) << 4)));
        S[0][j] = __builtin_amdgcn_mfma_f32_16x16x32_bf16(Kf, Qf[0][ks], S[0][j], 0, 0, 0);
        S[1][j] = __builtin_amdgcn_mfma_f32_16x16x32_bf16(Kf, Qf[1][ks], S[1][j], 0, 0, 0);
      }
    }
    __builtin_amdgcn_s_setprio(0);

    // online softmax: shfl-free common path
    bf16x8 Pf8[2];
#pragma unroll
    for (int qg = 0; qg < 2; qg++) {
      const float mxl =
          fmaxf(fmaxf(fmaxf(S[qg][0][0], S[qg][0][1]), fmaxf(S[qg][0][2], S[qg][0][3])),
                fmaxf(fmaxf(S[qg][1][0], S[qg][1][1]), fmaxf(S[qg][1][2], S[qg][1][3])));
      if (!__all(mxl <= mrow[qg] + 8.f)) {
        float mx = fmaxf(mxl, __shfl_xor(mxl, 16, 64));
        mx = fmaxf(mx, __shfl_xor(mx, 32, 64));
        const float mn = fmaxf(mrow[qg], mx);
        const float rs_ = exp2f(mrow[qg] - mn);
        mrow[qg] = mn;
        lrow[qg] *= rs_;
#pragma unroll
        for (int dg = 0; dg < 16; dg++) O[qg][dg] *= rs_;
      }
      float sum = 0.f;
      float e[2][4];
#pragma unroll
      for (int j = 0; j < 2; j++)
#pragma unroll
        for (int r = 0; r < 4; r++) {
          e[j][r] = exp2f(S[qg][j][r] - mrow[qg]);
          sum += e[j][r];
        }
      lrow[qg] += sum;  // per-lane partial
      bf16x8 p;
#pragma unroll
      for (int j = 0; j < 2; j++)
#pragma unroll
        for (int r = 0; r < 4; r++) p[j * 4 + r] = (short)f2b(e[j][r]);
      Pf8[qg] = p;
    }

    // PV: O^T += V' P'  (one 16x16x32 per (qg,dg); V-frag shared across qg)
    __builtin_amdgcn_s_setprio(1);
#pragma unroll
    for (int dg = 0; dg < 16; dg++) {
      bf16x8 Vf8 = *(const bf16x8*)(Vb + (dg * 16 + l15) * 64 +
                                    ((hi * 16) ^ ((l15 & 3) << 4)));
      O[0][dg] = __builtin_amdgcn_mfma_f32_16x16x32_bf16(Vf8, Pf8[0], O[0][dg], 0, 0, 0);
      O[1][dg] = __builtin_amdgcn_mfma_f32_16x16x32_bf16(Vf8, Pf8[1], O[1][dg], 0, 0, 0);
    }
    __builtin_amdgcn_s_setprio(0);
  }

  // epilogue: reduce lrow across hi, then UNNORMALIZED O^T -> slab -> partial out
  unsigned short* const op = kh ? o1 : o0;
  float2* const mlp = kh ? ml1 : ml0;
  __syncthreads();  // everyone done with K/V buffers
  char* const slab = lds + w * 16384;
#pragma unroll
  for (int qg = 0; qg < 2; qg++) {
    float lr = lrow[qg];
    lr += __shfl_xor(lr, 16, 64);
    lr += __shfl_xor(lr, 32, 64);
#pragma unroll
    for (int dg = 0; dg < 16; dg++) {
      f32x4 v = O[qg][dg];
      *(f32x4*)(slab + l15 * 1024 + ((dg * 64 + hi * 16) ^ ((l15 & 7) << 4))) = v;
    }
    if (hi == 0) mlp[qrow + qg * 16 + l15] = make_float2(mrow[qg], lr);
    const int qq = lane >> 2;
    const int dc = lane & 3;
    const long long orow = (qrow + qg * 16 + qq) * 256 + dc * 64;
#pragma unroll
    for (int half = 0; half < 8; half++) {
      bf16x8 pack;
#pragma unroll
      for (int di = 0; di < 2; di++) {
        f32x4 v = *(const f32x4*)(slab + qq * 1024 +
                                  ((dc * 256 + half * 32 + di * 16) ^ ((qq & 7) << 4)));
#pragma unroll
        for (int e2 = 0; e2 < 4; e2++) pack[di * 4 + e2] = (short)f2b(v[e2]);
      }
      *(bf16x8*)(op + orow + half * 8) = pack;
    }
    __syncthreads();  // slab reuse between qg passes
  }
}

// ---------------------------------------------------------------------------
extern "C" void kernel_launch(void* const* d_in, const int* in_sizes, int n_in,
                              void* d_out, int out_size, void* d_ws, size_t ws_size,
                              hipStream_t stream)
{
  const float* x = (const float*)d_in[0];
  const float* gamma = (const float*)d_in[1];
  const float* beta = (const float*)d_in[2];
  const float* wq = (const float*)d_in[3];
  const float* bq = (const float*)d_in[4];
  const float* wk = (const float*)d_in[5];
  const float* bk = (const float*)d_in[6];
  const float* wv = (const float*)d_in[7];
  const float* bv = (const float*)d_in[8];
  const float* wo = (const float*)d_in[9];
  const float* bo = (const float*)d_in[10];

  const int Cc = 256;
  const long long MR = 32768;  // 8 * 4096

  char* base = (char*)d_ws;
  size_t off = 0;
  auto take = [&](size_t bytes) -> char* {
    char* p = base + off;
    off = (off + bytes + 255) & ~(size_t)255;
    return p;
  };
  unsigned short* h   = (unsigned short*)take((size_t)MR * Cc * 2);
  unsigned short* q   = (unsigned short*)take((size_t)MR * Cc * 2);  // scaled
  unsigned short* kk  = (unsigned short*)take((size_t)MR * Cc * 2);
  unsigned short* vT  = (unsigned short*)take((size_t)MR * Cc * 2);  // [B][C][4096] k-perm
  unsigned short* o0  = (unsigned short*)take((size_t)MR * Cc * 2);  // partial kh=0
  unsigned short* o1  = (unsigned short*)take((size_t)MR * Cc * 2);  // partial kh=1
  unsigned short* wT  = (unsigned short*)take(4ull * Cc * Cc * 2);
  float2* ml0 = (float2*)take((size_t)MR * sizeof(float2));
  float2* ml1 = (float2*)take((size_t)MR * sizeof(float2));

  wtrans<<<dim3(16, 16, 4), dim3(16, 16), 0, stream>>>(wq, wk, wv, wo, wT);
  ln_bf16<<<dim3((unsigned)(MR / 8)), dim3(512), 0, stream>>>(x, gamma, beta, h);

  const float qscale = 0.0625f * 1.44269504f;  // 1/sqrt(256) * log2(e)
  gemm_qkv<<<dim3(2, 256, 3), 256, 0, stream>>>(h, wT, bq, bk, bv, q, kk, vT, qscale);

  flash<<<dim3(512), dim3(256), FL_LDS, stream>>>(q, kk, vT, o0, o1, ml0, ml1);

  gemm_out<<<dim3(2, 256, 1), 256, 0, stream>>>(o0, o1, ml0, ml1, wT + 3 * 65536,
                                                (float*)d_out, bo, x);
}